// Round 1
// baseline (1005.335 us; speedup 1.0000x reference)
//
#include <hip/hip_runtime.h>
#include <stdint.h>

#define NN 4096
#define TT 10
#define FF 512
#define NHID 64
#define NCLASS 16

#define G1_BM 128
#define G1_BK 64
#define G1_SPLITS 8   // j-range 512 per block, 32x8 = 256 blocks
#define G2_BM 64
#define G2_BK 64
#define G2_SPLITS 16  // j-range 256 per block, 64x16 = 1024 blocks

// ---------------- fold: A[i][j] = scan over adj[t][i][j] ----------------
__global__ void fold_k(const float4* __restrict__ adj, float4* __restrict__ A,
                       const float* __restrict__ lam_p) {
    const float lam = lam_p[0];
    const float w = 1.0f - lam;
    const int64_t slice = (int64_t)NN * NN / 4;  // float4s per slice
    const int64_t stride = (int64_t)gridDim.x * blockDim.x;
    for (int64_t i = (int64_t)blockIdx.x * blockDim.x + threadIdx.x; i < slice; i += stride) {
        float4 v = adj[i];
#pragma unroll
        for (int t = 1; t < TT; ++t) {
            float4 a = adj[(int64_t)t * slice + i];
            v.x = w * v.x + lam * a.x;
            v.y = w * v.y + lam * a.y;
            v.z = w * v.z + lam * a.z;
            v.w = w * v.w + lam * a.w;
        }
        A[i] = v;
    }
}

// ---------------- XW1_T[k][n] = sum_f feats[n][9][f] * W1[f][k] ----------------
__global__ __launch_bounds__(64) void xw1_k(const float* __restrict__ feats,
                                            const float* __restrict__ W1,
                                            float* __restrict__ XW1T) {
    __shared__ float xs[FF];
    const int n = blockIdx.x;
    const int k = threadIdx.x;
    const float4* xr4 = (const float4*)(feats + ((int64_t)n * TT + (TT - 1)) * FF);
    float4* xs4 = (float4*)xs;
#pragma unroll
    for (int f = k; f < FF / 4; f += 64) xs4[f] = xr4[f];
    __syncthreads();
    float acc = 0.0f;
#pragma unroll 8
    for (int f = 0; f < FF; ++f) acc = fmaf(xs[f], W1[f * NHID + k], acc);
    XW1T[(int64_t)k * NN + n] = acc;
}

// ---------------- GEMM1: Y1P[s][n][k] = partial of A @ XW1 ----------------
// block: 256 thr = 16(tr) x 16(tc); thread owns rows {r*16+tr, r<8}, cols {c*16+tc, c<4}
__global__ __launch_bounds__(256) void gemm1_k(const float* __restrict__ A,
                                               const float* __restrict__ XW1T,
                                               float* __restrict__ Y1P) {
    __shared__ float As[G1_BM][G1_BK + 4];
    __shared__ float Bs[NHID][G1_BK + 4];
    const int t = threadIdx.x;
    const int r0 = blockIdx.y * G1_BM;
    const int s = blockIdx.x;
    const int jbase = s * (NN / G1_SPLITS);
    const int tr = t >> 4;
    const int tc = t & 15;

    float acc[8][4];
#pragma unroll
    for (int r = 0; r < 8; ++r)
#pragma unroll
        for (int c = 0; c < 4; ++c) acc[r][c] = 0.0f;

    for (int tile = 0; tile < (NN / G1_SPLITS) / G1_BK; ++tile) {
        const int j0 = jbase + tile * G1_BK;
        // stage A tile 128x64: 2048 float4, 8/thread
#pragma unroll
        for (int u = 0; u < 8; ++u) {
            int idx = t + u * 256;
            int row = idx >> 4;
            int c4 = idx & 15;
            float4 v = *(const float4*)(A + (int64_t)(r0 + row) * NN + j0 + c4 * 4);
            *(float4*)&As[row][c4 * 4] = v;
        }
        // stage B tile 64x64: 1024 float4, 4/thread
#pragma unroll
        for (int u = 0; u < 4; ++u) {
            int idx = t + u * 256;
            int row = idx >> 4;
            int c4 = idx & 15;
            float4 v = *(const float4*)(XW1T + (int64_t)row * NN + j0 + c4 * 4);
            *(float4*)&Bs[row][c4 * 4] = v;
        }
        __syncthreads();
#pragma unroll 2
        for (int kk = 0; kk < G1_BK; kk += 4) {
            float4 a[8], b[4];
#pragma unroll
            for (int r = 0; r < 8; ++r) a[r] = *(const float4*)&As[r * 16 + tr][kk];
#pragma unroll
            for (int c = 0; c < 4; ++c) b[c] = *(const float4*)&Bs[c * 16 + tc][kk];
#pragma unroll
            for (int r = 0; r < 8; ++r)
#pragma unroll
                for (int c = 0; c < 4; ++c) {
                    float v = acc[r][c];
                    v = fmaf(a[r].x, b[c].x, v);
                    v = fmaf(a[r].y, b[c].y, v);
                    v = fmaf(a[r].z, b[c].z, v);
                    v = fmaf(a[r].w, b[c].w, v);
                    acc[r][c] = v;
                }
        }
        __syncthreads();
    }
    float* out = Y1P + (int64_t)s * NN * NHID;
#pragma unroll
    for (int r = 0; r < 8; ++r) {
        int n = r0 + r * 16 + tr;
#pragma unroll
        for (int c = 0; c < 4; ++c) out[(int64_t)n * NHID + c * 16 + tc] = acc[r][c];
    }
}

// ---------------- h = relu(sum_s Y1P + b1); HW2T[c][n] = h @ W2 ----------------
__global__ __launch_bounds__(256) void hw2_k(const float* __restrict__ Y1P,
                                             const float* __restrict__ b1,
                                             const float* __restrict__ W2,
                                             float* __restrict__ HW2T) {
    __shared__ float hs[4][NHID];
    const int row = threadIdx.x >> 6;
    const int k = threadIdx.x & 63;
    const int n = blockIdx.x * 4 + row;
    float v = b1[k];
#pragma unroll
    for (int s = 0; s < G1_SPLITS; ++s)
        v += Y1P[(int64_t)s * NN * NHID + (int64_t)n * NHID + k];
    hs[row][k] = fmaxf(v, 0.0f);
    __syncthreads();
    if (k < NCLASS) {
        float acc = 0.0f;
#pragma unroll
        for (int j = 0; j < NHID; ++j) acc = fmaf(hs[row][j], W2[j * NCLASS + k], acc);
        HW2T[(int64_t)k * NN + n] = acc;
    }
}

// ---------------- GEMM2: LP[s][n][c] = partial of A @ hW2 ----------------
// block: 64 thr = 16(tr) x 4(tc); thread owns rows {r*16+tr, r<4}, cols {c*4+tc, c<4}
__global__ __launch_bounds__(64) void gemm2_k(const float* __restrict__ A,
                                              const float* __restrict__ HW2T,
                                              float* __restrict__ LP) {
    __shared__ float As[G2_BM][G2_BK + 4];
    __shared__ float Bs[NCLASS][G2_BK + 4];
    const int t = threadIdx.x;
    const int r0 = blockIdx.y * G2_BM;
    const int s = blockIdx.x;
    const int jbase = s * (NN / G2_SPLITS);
    const int tr = t >> 2;
    const int tc = t & 3;

    float acc[4][4];
#pragma unroll
    for (int r = 0; r < 4; ++r)
#pragma unroll
        for (int c = 0; c < 4; ++c) acc[r][c] = 0.0f;

    for (int tile = 0; tile < (NN / G2_SPLITS) / G2_BK; ++tile) {
        const int j0 = jbase + tile * G2_BK;
        // stage A tile 64x64: 1024 float4, 16/thread
#pragma unroll
        for (int u = 0; u < 16; ++u) {
            int idx = t + u * 64;
            int row = idx >> 4;
            int c4 = idx & 15;
            *(float4*)&As[row][c4 * 4] =
                *(const float4*)(A + (int64_t)(r0 + row) * NN + j0 + c4 * 4);
        }
        // stage B tile 16x64: 256 float4, 4/thread
#pragma unroll
        for (int u = 0; u < 4; ++u) {
            int idx = t + u * 64;
            int row = idx >> 4;
            int c4 = idx & 15;
            *(float4*)&Bs[row][c4 * 4] =
                *(const float4*)(HW2T + (int64_t)row * NN + j0 + c4 * 4);
        }
        __syncthreads();
#pragma unroll 2
        for (int kk = 0; kk < G2_BK; kk += 4) {
            float4 a[4], b[4];
#pragma unroll
            for (int r = 0; r < 4; ++r) a[r] = *(const float4*)&As[r * 16 + tr][kk];
#pragma unroll
            for (int c = 0; c < 4; ++c) b[c] = *(const float4*)&Bs[c * 4 + tc][kk];
#pragma unroll
            for (int r = 0; r < 4; ++r)
#pragma unroll
                for (int c = 0; c < 4; ++c) {
                    float v = acc[r][c];
                    v = fmaf(a[r].x, b[c].x, v);
                    v = fmaf(a[r].y, b[c].y, v);
                    v = fmaf(a[r].z, b[c].z, v);
                    v = fmaf(a[r].w, b[c].w, v);
                    acc[r][c] = v;
                }
        }
        __syncthreads();
    }
    float* out = LP + (int64_t)s * NN * NCLASS;
#pragma unroll
    for (int r = 0; r < 4; ++r) {
        int n = r0 + r * 16 + tr;
#pragma unroll
        for (int c = 0; c < 4; ++c) out[(int64_t)n * NCLASS + c * 4 + tc] = acc[r][c];
    }
}

// ---------------- softmax over reduced logits ----------------
__global__ __launch_bounds__(256) void softmax_k(const float* __restrict__ LP,
                                                 const float* __restrict__ b2,
                                                 float* __restrict__ outp) {
    const int n = blockIdx.x * blockDim.x + threadIdx.x;  // 0..4095
    float l[NCLASS];
#pragma unroll
    for (int c = 0; c < NCLASS; ++c) l[c] = b2[c];
#pragma unroll
    for (int s = 0; s < G2_SPLITS; ++s) {
        const float4* p = (const float4*)(LP + (int64_t)s * NN * NCLASS + (int64_t)n * NCLASS);
#pragma unroll
        for (int q = 0; q < 4; ++q) {
            float4 v = p[q];
            l[q * 4 + 0] += v.x;
            l[q * 4 + 1] += v.y;
            l[q * 4 + 2] += v.z;
            l[q * 4 + 3] += v.w;
        }
    }
    float m = l[0];
#pragma unroll
    for (int c = 1; c < NCLASS; ++c) m = fmaxf(m, l[c]);
    float sum = 0.0f;
#pragma unroll
    for (int c = 0; c < NCLASS; ++c) {
        l[c] = __expf(l[c] - m);
        sum += l[c];
    }
    float inv = 1.0f / sum;
    float4* o = (float4*)(outp + (int64_t)n * NCLASS);
#pragma unroll
    for (int q = 0; q < 4; ++q)
        o[q] = make_float4(l[q * 4 + 0] * inv, l[q * 4 + 1] * inv, l[q * 4 + 2] * inv,
                           l[q * 4 + 3] * inv);
}

extern "C" void kernel_launch(void* const* d_in, const int* in_sizes, int n_in,
                              void* d_out, int out_size, void* d_ws, size_t ws_size,
                              hipStream_t stream) {
    const float* feats = (const float*)d_in[0];
    const float* adj = (const float*)d_in[1];
    const float* lam = (const float*)d_in[2];
    const float* W1 = (const float*)d_in[3];
    const float* b1 = (const float*)d_in[4];
    const float* W2 = (const float*)d_in[5];
    const float* b2 = (const float*)d_in[6];
    float* out = (float*)d_out;

    float* ws = (float*)d_ws;
    float* A = ws;                                        // 4096*4096        = 16777216
    float* XW1T = A + (int64_t)NN * NN;                   // 64*4096          = 262144
    float* Y1P = XW1T + (int64_t)NHID * NN;               // 8*4096*64        = 2097152
    float* HW2T = Y1P + (int64_t)G1_SPLITS * NN * NHID;   // 16*4096          = 65536
    float* LP = HW2T + (int64_t)NCLASS * NN;              // 16*4096*16       = 1048576

    fold_k<<<4096, 256, 0, stream>>>((const float4*)adj, (float4*)A, lam);
    xw1_k<<<NN, 64, 0, stream>>>(feats, W1, XW1T);
    gemm1_k<<<dim3(G1_SPLITS, NN / G1_BM), 256, 0, stream>>>(A, XW1T, Y1P);
    hw2_k<<<NN / 4, 256, 0, stream>>>(Y1P, b1, W2, HW2T);
    gemm2_k<<<dim3(G2_SPLITS, NN / G2_BM), 64, 0, stream>>>(A, HW2T, LP);
    softmax_k<<<NN / 256, 256, 0, stream>>>(LP, b2, out);
}

// Round 2
// 969.768 us; speedup vs baseline: 1.0367x; 1.0367x over previous
//
#include <hip/hip_runtime.h>
#include <stdint.h>

#define NN 4096
#define TT 10
#define FF 512
#define NHID 64
#define NCLASS 16

#define G1_BM 128
#define G1_BK 64
#define G1_SPLITS 16  // j-range 256/block; grid 16x32=512 blocks, 2/CU
#define G2_BM 128
#define G2_BK 64
#define G2_SPLITS 16

// ---------------- XW1_T[k][n] = sum_f feats[n][9][f] * W1[f][k] ----------------
// 16 rows per block; W1[f][k] loaded once per f-step, shared across 4 row-accs.
__global__ __launch_bounds__(256) void xw1_k(const float* __restrict__ feats,
                                             const float* __restrict__ W1,
                                             float* __restrict__ XW1T) {
    __shared__ float xs[16][FF];
    const int t = threadIdx.x;
    const int n0 = blockIdx.x * 16;
    // stage 16 feature rows: 2048 float4, 8/thread
#pragma unroll
    for (int u = 0; u < 8; ++u) {
        int idx = t + u * 256;
        int row = idx >> 7;       // 0..15
        int c4 = idx & 127;       // 0..127
        ((float4*)xs[row])[c4] =
            ((const float4*)(feats + ((int64_t)(n0 + row) * TT + (TT - 1)) * FF))[c4];
    }
    __syncthreads();
    const int k = t & 63;
    const int rl = t >> 6;  // wave id 0..3 -> rows rl*4 .. rl*4+3
    float acc[4] = {0.0f, 0.0f, 0.0f, 0.0f};
#pragma unroll 8
    for (int f = 0; f < FF; ++f) {
        float wv = W1[f * NHID + k];
#pragma unroll
        for (int r = 0; r < 4; ++r) acc[r] = fmaf(xs[rl * 4 + r][f], wv, acc[r]);
    }
#pragma unroll
    for (int r = 0; r < 4; ++r) XW1T[(int64_t)k * NN + n0 + rl * 4 + r] = acc[r];
}

// ------- fused fold + GEMM1: compute A-tile from adj, write A, accumulate A@XW1 -------
// block: 256 thr = 16(tr) x 16(tc); thread owns rows {r*16+tr, r<8}, cols {c*16+tc, c<4}
__global__ __launch_bounds__(256) void foldgemm1_k(const float* __restrict__ adj,
                                                   const float* __restrict__ lam_p,
                                                   const float* __restrict__ XW1T,
                                                   float* __restrict__ A,
                                                   float* __restrict__ Y1P) {
    __shared__ float As[G1_BM][G1_BK + 4];
    __shared__ float Bs[NHID][G1_BK + 4];
    const float lam = lam_p[0];
    const float w = 1.0f - lam;
    const int t = threadIdx.x;
    const int r0 = blockIdx.y * G1_BM;
    const int s = blockIdx.x;
    const int jbase = s * (NN / G1_SPLITS);
    const int tr = t >> 4;
    const int tc = t & 15;
    const int64_t slice = (int64_t)NN * NN;

    float acc[8][4];
#pragma unroll
    for (int r = 0; r < 8; ++r)
#pragma unroll
        for (int c = 0; c < 4; ++c) acc[r][c] = 0.0f;

    for (int tile = 0; tile < (NN / G1_SPLITS) / G1_BK; ++tile) {  // 4 K-tiles
        const int j0 = jbase + tile * G1_BK;
        // fold-stage A tile 128x64: 2048 float4-sites, 8/thread.
        // unroll 2: ~20 outstanding 16B loads/thread bounds VGPR while keeping MLP.
#pragma unroll 2
        for (int u = 0; u < 8; ++u) {
            int idx = t + u * 256;
            int row = idx >> 4;
            int c4 = idx & 15;
            const float* p = adj + (int64_t)(r0 + row) * NN + j0 + c4 * 4;
            float4 v = *(const float4*)p;
#pragma unroll
            for (int tt = 1; tt < TT; ++tt) {
                float4 a = *(const float4*)(p + (int64_t)tt * slice);
                v.x = fmaf(lam, a.x, w * v.x);
                v.y = fmaf(lam, a.y, w * v.y);
                v.z = fmaf(lam, a.z, w * v.z);
                v.w = fmaf(lam, a.w, w * v.w);
            }
            *(float4*)&As[row][c4 * 4] = v;
            *(float4*)(A + (int64_t)(r0 + row) * NN + j0 + c4 * 4) = v;
        }
        // stage B tile 64x64: 1024 float4, 4/thread
#pragma unroll
        for (int u = 0; u < 4; ++u) {
            int idx = t + u * 256;
            int row = idx >> 4;
            int c4 = idx & 15;
            *(float4*)&Bs[row][c4 * 4] =
                *(const float4*)(XW1T + (int64_t)row * NN + j0 + c4 * 4);
        }
        __syncthreads();
#pragma unroll 2
        for (int kk = 0; kk < G1_BK; kk += 4) {
            float4 a[8], b[4];
#pragma unroll
            for (int r = 0; r < 8; ++r) a[r] = *(const float4*)&As[r * 16 + tr][kk];
#pragma unroll
            for (int c = 0; c < 4; ++c) b[c] = *(const float4*)&Bs[c * 16 + tc][kk];
#pragma unroll
            for (int r = 0; r < 8; ++r)
#pragma unroll
                for (int c = 0; c < 4; ++c) {
                    float v = acc[r][c];
                    v = fmaf(a[r].x, b[c].x, v);
                    v = fmaf(a[r].y, b[c].y, v);
                    v = fmaf(a[r].z, b[c].z, v);
                    v = fmaf(a[r].w, b[c].w, v);
                    acc[r][c] = v;
                }
        }
        __syncthreads();
    }
    float* out = Y1P + (int64_t)s * NN * NHID;
#pragma unroll
    for (int r = 0; r < 8; ++r) {
        int n = r0 + r * 16 + tr;
#pragma unroll
        for (int c = 0; c < 4; ++c) out[(int64_t)n * NHID + c * 16 + tc] = acc[r][c];
    }
}

// ---------------- h = relu(sum_s Y1P + b1); HW2T[c][n] = h @ W2 ----------------
__global__ __launch_bounds__(256) void hw2_k(const float* __restrict__ Y1P,
                                             const float* __restrict__ b1,
                                             const float* __restrict__ W2,
                                             float* __restrict__ HW2T) {
    __shared__ float hs[4][NHID];
    const int row = threadIdx.x >> 6;
    const int k = threadIdx.x & 63;
    const int n = blockIdx.x * 4 + row;
    float v = b1[k];
#pragma unroll
    for (int s = 0; s < G1_SPLITS; ++s)
        v += Y1P[(int64_t)s * NN * NHID + (int64_t)n * NHID + k];
    hs[row][k] = fmaxf(v, 0.0f);
    __syncthreads();
    if (k < NCLASS) {
        float acc = 0.0f;
#pragma unroll
        for (int j = 0; j < NHID; ++j) acc = fmaf(hs[row][j], W2[j * NCLASS + k], acc);
        HW2T[(int64_t)k * NN + n] = acc;
    }
}

// ---------------- GEMM2: LP[s][n][c] = partial of A @ hW2 ----------------
// block: 256 thr = 32(tr) x 8(tc); thread owns rows {r*32+tr, r<4}, cols {c*8+tc, c<2}
__global__ __launch_bounds__(256) void gemm2_k(const float* __restrict__ A,
                                               const float* __restrict__ HW2T,
                                               float* __restrict__ LP) {
    __shared__ float As[G2_BM][G2_BK + 4];
    __shared__ float Bs[NCLASS][G2_BK + 4];
    const int t = threadIdx.x;
    const int r0 = blockIdx.y * G2_BM;
    const int s = blockIdx.x;
    const int jbase = s * (NN / G2_SPLITS);
    const int tr = t >> 3;  // 0..31
    const int tc = t & 7;   // 0..7

    float acc[4][2];
#pragma unroll
    for (int r = 0; r < 4; ++r)
#pragma unroll
        for (int c = 0; c < 2; ++c) acc[r][c] = 0.0f;

    for (int tile = 0; tile < (NN / G2_SPLITS) / G2_BK; ++tile) {  // 4
        const int j0 = jbase + tile * G2_BK;
        // stage A tile 128x64: 2048 float4, 8/thread
#pragma unroll
        for (int u = 0; u < 8; ++u) {
            int idx = t + u * 256;
            int row = idx >> 4;
            int c4 = idx & 15;
            *(float4*)&As[row][c4 * 4] =
                *(const float4*)(A + (int64_t)(r0 + row) * NN + j0 + c4 * 4);
        }
        // stage B tile 16x64: 256 float4, 1/thread
        {
            int row = t >> 4;
            int c4 = t & 15;
            *(float4*)&Bs[row][c4 * 4] =
                *(const float4*)(HW2T + (int64_t)row * NN + j0 + c4 * 4);
        }
        __syncthreads();
#pragma unroll 2
        for (int kk = 0; kk < G2_BK; kk += 4) {
            float4 a[4], b[2];
#pragma unroll
            for (int r = 0; r < 4; ++r) a[r] = *(const float4*)&As[r * 32 + tr][kk];
#pragma unroll
            for (int c = 0; c < 2; ++c) b[c] = *(const float4*)&Bs[c * 8 + tc][kk];
#pragma unroll
            for (int r = 0; r < 4; ++r)
#pragma unroll
                for (int c = 0; c < 2; ++c) {
                    float v = acc[r][c];
                    v = fmaf(a[r].x, b[c].x, v);
                    v = fmaf(a[r].y, b[c].y, v);
                    v = fmaf(a[r].z, b[c].z, v);
                    v = fmaf(a[r].w, b[c].w, v);
                    acc[r][c] = v;
                }
        }
        __syncthreads();
    }
    float* out = LP + (int64_t)s * NN * NCLASS;
#pragma unroll
    for (int r = 0; r < 4; ++r) {
        int n = r0 + r * 32 + tr;
#pragma unroll
        for (int c = 0; c < 2; ++c) out[(int64_t)n * NCLASS + c * 8 + tc] = acc[r][c];
    }
}

// ---------------- softmax over reduced logits ----------------
__global__ __launch_bounds__(256) void softmax_k(const float* __restrict__ LP,
                                                 const float* __restrict__ b2,
                                                 float* __restrict__ outp) {
    const int n = blockIdx.x * blockDim.x + threadIdx.x;  // 0..4095
    float l[NCLASS];
#pragma unroll
    for (int c = 0; c < NCLASS; ++c) l[c] = b2[c];
#pragma unroll
    for (int s = 0; s < G2_SPLITS; ++s) {
        const float4* p = (const float4*)(LP + (int64_t)s * NN * NCLASS + (int64_t)n * NCLASS);
#pragma unroll
        for (int q = 0; q < 4; ++q) {
            float4 v = p[q];
            l[q * 4 + 0] += v.x;
            l[q * 4 + 1] += v.y;
            l[q * 4 + 2] += v.z;
            l[q * 4 + 3] += v.w;
        }
    }
    float m = l[0];
#pragma unroll
    for (int c = 1; c < NCLASS; ++c) m = fmaxf(m, l[c]);
    float sum = 0.0f;
#pragma unroll
    for (int c = 0; c < NCLASS; ++c) {
        l[c] = __expf(l[c] - m);
        sum += l[c];
    }
    float inv = 1.0f / sum;
    float4* o = (float4*)(outp + (int64_t)n * NCLASS);
#pragma unroll
    for (int q = 0; q < 4; ++q)
        o[q] = make_float4(l[q * 4 + 0] * inv, l[q * 4 + 1] * inv, l[q * 4 + 2] * inv,
                           l[q * 4 + 3] * inv);
}

extern "C" void kernel_launch(void* const* d_in, const int* in_sizes, int n_in,
                              void* d_out, int out_size, void* d_ws, size_t ws_size,
                              hipStream_t stream) {
    const float* feats = (const float*)d_in[0];
    const float* adj = (const float*)d_in[1];
    const float* lam = (const float*)d_in[2];
    const float* W1 = (const float*)d_in[3];
    const float* b1 = (const float*)d_in[4];
    const float* W2 = (const float*)d_in[5];
    const float* b2 = (const float*)d_in[6];
    float* out = (float*)d_out;

    float* ws = (float*)d_ws;
    float* A = ws;                                       // 4096*4096   = 16777216
    float* XW1T = A + (int64_t)NN * NN;                  // 64*4096     = 262144
    float* Y1P = XW1T + (int64_t)NHID * NN;              // 16*4096*64  = 4194304
    float* HW2T = Y1P + (int64_t)G1_SPLITS * NN * NHID;  // 16*4096     = 65536
    float* LP = HW2T + (int64_t)NCLASS * NN;             // 16*4096*16  = 1048576

    xw1_k<<<NN / 16, 256, 0, stream>>>(feats, W1, XW1T);
    foldgemm1_k<<<dim3(G1_SPLITS, NN / G1_BM), 256, 0, stream>>>(adj, lam, XW1T, A, Y1P);
    hw2_k<<<NN / 4, 256, 0, stream>>>(Y1P, b1, W2, HW2T);
    gemm2_k<<<dim3(G2_SPLITS, NN / G2_BM), 256, 0, stream>>>(A, HW2T, LP);
    softmax_k<<<NN / 256, 256, 0, stream>>>(LP, b2, out);
}